// Round 9
// baseline (747.518 us; speedup 1.0000x reference)
//
#include <hip/hip_runtime.h>

#define RH 32
#define RT 2048
#define RC 10

typedef __attribute__((ext_vector_type(8))) _Float16 f16x8;
typedef __attribute__((ext_vector_type(4))) float f32x4;

#define MFMA16(a,b,c) __builtin_amdgcn_mfma_f32_16x16x32_f16((a),(b),(c),0,0,0)

// tanh(x) = 1 - 2/(exp(2x)+1); saturates correctly at +/-inf.
__device__ __forceinline__ float fast_tanh(float x) {
    float e = __builtin_amdgcn_exp2f(x * 2.88539008177792681472f);
    return fmaf(-2.0f, __builtin_amdgcn_rcpf(e + 1.0f), 1.0f);
}

// A-frag rows [base,base+16): lane(n,g) holds W[base+n][k], k = 4g+(e&3)+16*(e>>2)
// (layout validated end-to-end in rounds 4, 5, 7, 8)
__device__ __forceinline__ f16x8 load_wfrag16(const float* __restrict__ W,
                                              int base, int n, int g) {
    f16x8 f;
#pragma unroll
    for (int e = 0; e < 8; ++e) {
        int k = 4*g + (e & 3) + 16*(e >> 2);
        f[e] = (_Float16)W[(base + n)*RH + k];   // RNE
    }
    return f;
}

// Raw barrier: no vmcnt drain (keeps x loads in flight). Memory clobbers pin
// LDS/global ops to their phase; register values are unaffected.
#define BAR() do { __asm__ volatile("" ::: "memory"); \
                   __builtin_amdgcn_s_barrier(); \
                   __asm__ volatile("" ::: "memory"); } while (0)

__global__ __launch_bounds__(128) void rnn2_pipe2w_kernel(
    const float* __restrict__ x,
    const float* __restrict__ W_ih0, const float* __restrict__ W_hh0,
    const float* __restrict__ b_ih0, const float* __restrict__ b_hh0,
    const float* __restrict__ W_ih1, const float* __restrict__ W_hh1,
    const float* __restrict__ b_ih1, const float* __restrict__ b_hh1,
    const float* __restrict__ fc_w, const float* __restrict__ fc_b,
    float* __restrict__ out)
{
    __shared__ __align__(16) _Float16 hring[4][64][8];  // h1 frag handoff ring
    __shared__ float h2fin[16][RH];

    const int tid = threadIdx.x;
    const int wv  = tid >> 6;        // wave0 = layer1, wave1 = layer2
    const int ln  = tid & 63;
    const int n   = ln & 15;         // batch column
    const int g   = ln >> 4;         // row/k 4-group

    // Shared names: wave0 holds layer-1 weights, wave1 holds layer-2 weights.
    f16x8 Wa, Wb, WHa, WHb;
    f32x4 cba, cbb;
    if (wv == 0) {
        Wa  = load_wfrag16(W_ih0,  0, n, g);
        Wb  = load_wfrag16(W_ih0, 16, n, g);
        WHa = load_wfrag16(W_hh0,  0, n, g);
        WHb = load_wfrag16(W_hh0, 16, n, g);
#pragma unroll
        for (int i = 0; i < 4; ++i) {
            cba[i] = b_ih0[4*g + i]      + b_hh0[4*g + i];
            cbb[i] = b_ih0[16 + 4*g + i] + b_hh0[16 + 4*g + i];
        }
    } else {
        Wa  = load_wfrag16(W_ih1,  0, n, g);
        Wb  = load_wfrag16(W_ih1, 16, n, g);
        WHa = load_wfrag16(W_hh1,  0, n, g);
        WHb = load_wfrag16(W_hh1, 16, n, g);
#pragma unroll
        for (int i = 0; i < 4; ++i) {
            cba[i] = b_ih1[4*g + i]      + b_hh1[4*g + i];
            cbb[i] = b_ih1[16 + 4*g + i] + b_hh1[16 + 4*g + i];
        }
    }

    f16x8 hst;                       // wave0: h1 state, wave1: h2 state
#pragma unroll
    for (int e = 0; e < 8; ++e) hst[e] = (_Float16)0.0f;
    f16x8 R0 = hst, R1 = hst;        // wave1: incoming h1 frags (2-deep)

    const float* xp = x + (size_t)(blockIdx.x*16 + n) * (RT*RH) + 4*g;
    float4 A0, B0, A1, B1, A2, B2, A3, B3;   // wave0: 4-slot x register ring

#define PREF(A_, B_, T_) do { \
    const float* p_ = xp + (size_t)(T_) * RH; \
    A_ = *(const float4*)p_; \
    B_ = *(const float4*)(p_ + 16); \
} while (0)

#define CVTX(dst_, A_, B_) do { \
    auto q0_ = __builtin_amdgcn_cvt_pkrtz(A_.x, A_.y); \
    auto q1_ = __builtin_amdgcn_cvt_pkrtz(A_.z, A_.w); \
    auto q2_ = __builtin_amdgcn_cvt_pkrtz(B_.x, B_.y); \
    auto q3_ = __builtin_amdgcn_cvt_pkrtz(B_.z, B_.w); \
    dst_[0] = q0_[0]; dst_[1] = q0_[1]; dst_[2] = q1_[0]; dst_[3] = q1_[1]; \
    dst_[4] = q2_[0]; dst_[5] = q2_[1]; dst_[6] = q3_[0]; dst_[7] = q3_[1]; \
} while (0)

    // wave0 phase P_: h1(P_) = tanh(WI0.x(P_) + WH0.h1(P_-1) + b1); write slot.
#define STEPA(P_, SLOT_, SA_, SB_, DOPREF_) do { \
    f16x8 xf_; CVTX(xf_, SA_, SB_); \
    f32x4 d0_ = MFMA16(Wa, xf_, cba); \
    f32x4 d1_ = MFMA16(Wb, xf_, cbb); \
    d0_ = MFMA16(WHa, hst, d0_); \
    d1_ = MFMA16(WHb, hst, d1_); \
    if (DOPREF_) { PREF(SA_, SB_, (P_) + 4); } \
    _Pragma("unroll") \
    for (int i_ = 0; i_ < 4; ++i_) { d0_[i_] = fast_tanh(d0_[i_]); d1_[i_] = fast_tanh(d1_[i_]); } \
    _Pragma("unroll") \
    for (int i_ = 0; i_ < 4; ++i_) { hst[i_] = (_Float16)d0_[i_]; hst[4+i_] = (_Float16)d1_[i_]; } \
    *(f16x8*)&hring[SLOT_][ln][0] = hst; \
    __asm__ volatile("s_waitcnt lgkmcnt(0)" ::: "memory"); \
} while (0)

    // wave1 phase p: h2 = tanh(WI1.h1prev + WH1.h2 + b2); h1prev = RC_ (read
    // one phase earlier); issue read of slot RS_ into RN_ for next phase.
#define STEPB(RS_, RC_, RN_, DOREAD_) do { \
    f32x4 e0_ = MFMA16(Wa, RC_, cba); \
    f32x4 e1_ = MFMA16(Wb, RC_, cbb); \
    e0_ = MFMA16(WHa, hst, e0_); \
    e1_ = MFMA16(WHb, hst, e1_); \
    if (DOREAD_) { RN_ = *(const f16x8*)&hring[RS_][ln][0]; } \
    _Pragma("unroll") \
    for (int i_ = 0; i_ < 4; ++i_) { e0_[i_] = fast_tanh(e0_[i_]); e1_[i_] = fast_tanh(e1_[i_]); } \
    _Pragma("unroll") \
    for (int i_ = 0; i_ < 4; ++i_) { hst[i_] = (_Float16)e0_[i_]; hst[4+i_] = (_Float16)e1_[i_]; } \
} while (0)

    // ---- phase 0: wave0 computes h1(0) (h-term exactly zero, skipped) ----
    if (wv == 0) {
        PREF(A0, B0, 0); PREF(A1, B1, 1); PREF(A2, B2, 2); PREF(A3, B3, 3);
        f16x8 xf0; CVTX(xf0, A0, B0);
        f32x4 d0_ = MFMA16(Wa, xf0, cba);
        f32x4 d1_ = MFMA16(Wb, xf0, cbb);
        PREF(A0, B0, 4);
#pragma unroll
        for (int i = 0; i < 4; ++i) { d0_[i] = fast_tanh(d0_[i]); d1_[i] = fast_tanh(d1_[i]); }
#pragma unroll
        for (int i = 0; i < 4; ++i) { hst[i] = (_Float16)d0_[i]; hst[4+i] = (_Float16)d1_[i]; }
        *(f16x8*)&hring[0][ln][0] = hst;
        __asm__ volatile("s_waitcnt lgkmcnt(0)" ::: "memory");
    }
    BAR();
    // ---- phase 1: wave0 h1(1); wave1 prefetches h1(0) ----
    if (wv == 0) { STEPA(1, 1, A1, B1, 1); }
    else         { R0 = *(const f16x8*)&hring[0][ln][0]; }
    BAR();

    // ---- main loop: phases 2..2037 ----
    for (int k = 0; k < 509; ++k) {
        const int p = 4*k + 2;
        if (wv == 0) { STEPA(p,     2, A2, B2, 1); } else { STEPB(1, R0, R1, 1); }
        BAR();
        if (wv == 0) { STEPA(p + 1, 3, A3, B3, 1); } else { STEPB(2, R1, R0, 1); }
        BAR();
        if (wv == 0) { STEPA(p + 2, 0, A0, B0, 1); } else { STEPB(3, R0, R1, 1); }
        BAR();
        if (wv == 0) { STEPA(p + 3, 1, A1, B1, 1); } else { STEPB(0, R1, R0, 1); }
        BAR();
    }
    // ---- peel: phases 2038..2049 ----
    if (wv == 0) { STEPA(2038, 2, A2, B2, 1); } else { STEPB(1, R0, R1, 1); }
    BAR();
    if (wv == 0) { STEPA(2039, 3, A3, B3, 1); } else { STEPB(2, R1, R0, 1); }
    BAR();
    if (wv == 0) { STEPA(2040, 0, A0, B0, 1); } else { STEPB(3, R0, R1, 1); }
    BAR();
    if (wv == 0) { STEPA(2041, 1, A1, B1, 1); } else { STEPB(0, R1, R0, 1); }
    BAR();
    if (wv == 0) { STEPA(2042, 2, A2, B2, 1); } else { STEPB(1, R0, R1, 1); }
    BAR();
    if (wv == 0) { STEPA(2043, 3, A3, B3, 1); } else { STEPB(2, R1, R0, 1); }
    BAR();
    if (wv == 0) { STEPA(2044, 0, A0, B0, 0); } else { STEPB(3, R0, R1, 1); }
    BAR();
    if (wv == 0) { STEPA(2045, 1, A1, B1, 0); } else { STEPB(0, R1, R0, 1); }
    BAR();
    if (wv == 0) { STEPA(2046, 2, A2, B2, 0); } else { STEPB(1, R0, R1, 1); }
    BAR();
    if (wv == 0) { STEPA(2047, 3, A3, B3, 0); } else { STEPB(2, R1, R0, 1); }
    BAR();
    if (wv == 1) { STEPB(3, R0, R1, 1); }            // phase 2048: h2(2046)
    BAR();
    if (wv == 1) {                                    // phase 2049: h2(2047) -> f32
        f32x4 e0_ = MFMA16(Wa, R1, cba);
        f32x4 e1_ = MFMA16(Wb, R1, cbb);
        e0_ = MFMA16(WHa, hst, e0_);
        e1_ = MFMA16(WHb, hst, e1_);
#pragma unroll
        for (int i = 0; i < 4; ++i) { e0_[i] = fast_tanh(e0_[i]); e1_[i] = fast_tanh(e1_[i]); }
#pragma unroll
        for (int i = 0; i < 4; ++i) {
            h2fin[n][4*g + i]      = e0_[i];
            h2fin[n][16 + 4*g + i] = e1_[i];
        }
    }
    BAR();
#undef STEPA
#undef STEPB
#undef CVTX
#undef PREF

    // FC epilogue: wave1 only (same-wave LDS write->read, DS pipe in-order).
    if (wv == 1) {
        __asm__ volatile("" ::: "memory");
        for (int c = ln; c < 16 * RC; c += 64) {
            const int bt = c / RC;
            const int cl = c % RC;
            float s = fc_b[cl];
#pragma unroll
            for (int kk = 0; kk < RH; ++kk)
                s = fmaf(fc_w[cl*RH + kk], h2fin[bt][kk], s);
            out[(size_t)(blockIdx.x*16 + bt) * RC + cl] = s;
        }
    }
}

extern "C" void kernel_launch(void* const* d_in, const int* in_sizes, int n_in,
                              void* d_out, int out_size, void* d_ws, size_t ws_size,
                              hipStream_t stream) {
    const float* x     = (const float*)d_in[0];
    const float* W_ih0 = (const float*)d_in[1];
    const float* W_hh0 = (const float*)d_in[2];
    const float* b_ih0 = (const float*)d_in[3];
    const float* b_hh0 = (const float*)d_in[4];
    const float* W_ih1 = (const float*)d_in[5];
    const float* W_hh1 = (const float*)d_in[6];
    const float* b_ih1 = (const float*)d_in[7];
    const float* b_hh1 = (const float*)d_in[8];
    const float* fc_w  = (const float*)d_in[9];
    const float* fc_b  = (const float*)d_in[10];
    float* out = (float*)d_out;

    rnn2_pipe2w_kernel<<<32, 128, 0, stream>>>(x, W_ih0, W_hh0, b_ih0, b_hh0,
                                               W_ih1, W_hh1, b_ih1, b_hh1,
                                               fc_w, fc_b, out);
}